// Round 9
// baseline (36.691 us; speedup 1.0000x reference)
//
#include <hip/hip_runtime.h>

// out = Wv^T * X * Wv (softmax/log-Euclidean machinery collapses: wsum == 1).
// v9: NO X staging in LDS. Stage 1 is split by ROWS across waves (wave w owns
// T rows 32w..32w+31, all 64 cols), so each wave reads disjoint X A-fragments
// straight from global (X read exactly once per block, 128B-line panels) and
// feeds MFMA directly after one bf16 conversion. Both stage-1 B and stage-2 A
// operands are the same compile-time-indexed Wt[4][4] register array.
// LDS = one 16 KiB block-shared buffer for the T transposition; ONE barrier.
// One matrix per block: GRID=2048, no loops, no double-buffering.

typedef unsigned int uint;
typedef unsigned short ushort;
typedef __bf16 bf16x8 __attribute__((ext_vector_type(8)));
typedef float f32x4 __attribute__((ext_vector_type(4)));
typedef uint uint4v __attribute__((ext_vector_type(4)));
typedef uint uint2v __attribute__((ext_vector_type(2)));

#define DIN   128
#define DOUT  64
#define BLOCK 256
#define GRID  2048

#define MFMA(a, b, c) __builtin_amdgcn_mfma_f32_16x16x32_bf16((a), (b), (c), 0, 0, 0)

__device__ __forceinline__ ushort f2bf(float x) {           // RNE, exact
    uint u = __builtin_bit_cast(uint, x);
    u += 0x7FFFu + ((u >> 16) & 1u);
    return (ushort)(u >> 16);
}
__device__ __forceinline__ uint pk2(float a, float b) {     // lo16=a, hi16=b
    return (uint)f2bf(a) | ((uint)f2bf(b) << 16);
}

extern "C" __global__ void __launch_bounds__(BLOCK, 3)
spd_v9_kernel(const float* __restrict__ x, const float* __restrict__ wv,
              float* __restrict__ out)
{
    __shared__ char Tt[16384];              // T in B-fragment chunk order
    const int t    = threadIdx.x;
    const int lane = t & 63;
    const int w    = t >> 6;                // wave id 0..3
    const int c    = lane & 15;
    const int g    = lane >> 4;

    const float* X = x + (size_t)blockIdx.x * (DIN * DIN);

    // ---- issue ALL stage-1 A-fragment loads first (latency under Wt setup).
    // A row = 32w + 16mt + c, k-cols 32kb+8g .. +7 : 16 rows x 128B panels.
    const int arow = 32 * w + c;
    float4 xv[16];
#pragma unroll
    for (int mt = 0; mt < 2; ++mt)
#pragma unroll
        for (int kb = 0; kb < 4; ++kb) {
            const float* p = X + (size_t)(arow + 16 * mt) * DIN + kb * 32 + g * 8;
            xv[(mt * 4 + kb) * 2]     = *(const float4*)p;
            xv[(mt * 4 + kb) * 2 + 1] = *(const float4*)(p + 4);
        }

    // ---- Wt[idx][kb] = Wv[32kb+8g+j][16idx+c]  (regs, compile-time indexed)
    // Serves as stage-1 B operand (idx = column tile nt) AND stage-2 A
    // operand (idx = row tile mt2).
    bf16x8 Wt[4][4];
#pragma unroll
    for (int idx = 0; idx < 4; ++idx)
#pragma unroll
        for (int kb = 0; kb < 4; ++kb) {
            float f[8];
#pragma unroll
            for (int j = 0; j < 8; ++j)
                f[j] = wv[(kb * 32 + g * 8 + j) * DOUT + idx * 16 + c];
            uint4v u;
#pragma unroll
            for (int e = 0; e < 4; ++e) u[e] = pk2(f[2 * e], f[2 * e + 1]);
            Wt[idx][kb] = __builtin_bit_cast(bf16x8, u);
        }

    // ---- stage 1: T rows [32w,32w+32) = X-panel * Wv   (32 MFMA / wave)
    f32x4 Tacc[2][4] = {};
#pragma unroll
    for (int mt = 0; mt < 2; ++mt) {
        bf16x8 Af[4];
#pragma unroll
        for (int kb = 0; kb < 4; ++kb) {
            const int q = (mt * 4 + kb) * 2;
            uint4v u;
            u[0] = pk2(xv[q].x,     xv[q].y);
            u[1] = pk2(xv[q].z,     xv[q].w);
            u[2] = pk2(xv[q + 1].x, xv[q + 1].y);
            u[3] = pk2(xv[q + 1].z, xv[q + 1].w);
            Af[kb] = __builtin_bit_cast(bf16x8, u);
        }
#pragma unroll
        for (int nt = 0; nt < 4; ++nt)
#pragma unroll
            for (int kb = 0; kb < 4; ++kb)
                Tacc[mt][nt] = MFMA(Af[kb], Wt[nt][kb], Tacc[mt][nt]);
    }

    // ---- pack + write T into Tt, B-fragment chunk order.
    // T row k = 32w+16mt+4g+r, col n = 16nt+c ->
    // byte = ((kb_t*4+sub)*4+nt)*256 + c*16 + j*2,
    // kb_t = w, sub = 2mt+(g>>1), j = 4(g&1)+r.
#pragma unroll
    for (int mt = 0; mt < 2; ++mt)
#pragma unroll
        for (int nt = 0; nt < 4; ++nt) {
            uint2v p;
            p[0] = pk2(Tacc[mt][nt][0], Tacc[mt][nt][1]);
            p[1] = pk2(Tacc[mt][nt][2], Tacc[mt][nt][3]);
            const int byte = ((w * 4 + 2 * mt + (g >> 1)) * 4 + nt) * 256
                           + c * 16 + (g & 1) * 8;
            *(uint2v*)(Tt + byte) = p;
        }
    __syncthreads();

    // ---- stage 2: O = Wv^T * T ; wave w owns O cols 16w..16w+15 (16 MFMA)
    bf16x8 Bt[4];
#pragma unroll
    for (int kb = 0; kb < 4; ++kb)
        Bt[kb] = *(const bf16x8*)(Tt + ((kb * 4 + g) * 4 + w) * 256 + c * 16);

    float* ob = out + (size_t)blockIdx.x * (DOUT * DOUT)
              + (size_t)(g * 4) * DOUT + w * 16 + c;
#pragma unroll
    for (int mt2 = 0; mt2 < 4; ++mt2) {
        f32x4 acc = {0.f, 0.f, 0.f, 0.f};
#pragma unroll
        for (int kb = 0; kb < 4; ++kb)
            acc = MFMA(Wt[mt2][kb], Bt[kb], acc);
#pragma unroll
        for (int r = 0; r < 4; ++r)
            ob[(size_t)(mt2 * 16 + r) * DOUT] = acc[r];
    }
}

extern "C" void kernel_launch(void* const* d_in, const int* in_sizes, int n_in,
                              void* d_out, int out_size, void* d_ws, size_t ws_size,
                              hipStream_t stream)
{
    const float* x  = (const float*)d_in[0];   // (32,64,128,128) fp32
    const float* wv = (const float*)d_in[3];   // (128,64) fp32
    float* out = (float*)d_out;                // (2048,64,64) fp32

    (void)in_sizes; (void)n_in; (void)d_ws; (void)ws_size; (void)out_size;

    hipLaunchKernelGGL(spd_v9_kernel, dim3(GRID), dim3(BLOCK), 0, stream,
                       x, wv, out);
}

// Round 10
// 32.006 us; speedup vs baseline: 1.1464x; 1.1464x over previous
//
#include <hip/hip_runtime.h>

// out = Wv^T * X * Wv (softmax/log-Euclidean machinery collapses: wsum == 1).
// v10 = v9 row-split dataflow (X straight from global into MFMA A-fragments,
// read exactly once per block; only T's transposition goes through LDS) with
// the Wv fragment set moved from 64 VGPRs into 16 KiB LDS (WtL). This cuts
// the live set from ~190 (v9: spilled under lb(256,3)) to ~120-130 regs, so
// 3 blocks/CU (12 waves) is an honest fit. LDS total 32 KiB; 2 barriers.

typedef unsigned int uint;
typedef unsigned short ushort;
typedef __bf16 bf16x8 __attribute__((ext_vector_type(8)));
typedef float f32x4 __attribute__((ext_vector_type(4)));
typedef uint uint4v __attribute__((ext_vector_type(4)));
typedef uint uint2v __attribute__((ext_vector_type(2)));

#define DIN   128
#define DOUT  64
#define BLOCK 256
#define GRID  2048

#define MFMA(a, b, c) __builtin_amdgcn_mfma_f32_16x16x32_bf16((a), (b), (c), 0, 0, 0)

__device__ __forceinline__ ushort f2bf(float x) {           // RNE, exact
    uint u = __builtin_bit_cast(uint, x);
    u += 0x7FFFu + ((u >> 16) & 1u);
    return (ushort)(u >> 16);
}
__device__ __forceinline__ uint pk2(float a, float b) {     // lo16=a, hi16=b
    return (uint)f2bf(a) | ((uint)f2bf(b) << 16);
}

extern "C" __global__ void __launch_bounds__(BLOCK, 3)
spd_v10_kernel(const float* __restrict__ x, const float* __restrict__ wv,
               float* __restrict__ out)
{
    __shared__ char WtL[16384];   // Wv fragments: frag(idx,kb), lane l -> 16B
    __shared__ char Tt[16384];    // T in B-fragment chunk order (v9 mapping)
    const int t    = threadIdx.x;
    const int lane = t & 63;
    const int w    = t >> 6;      // wave id 0..3
    const int c    = lane & 15;
    const int g    = lane >> 4;

    const float* X = x + (size_t)blockIdx.x * (DIN * DIN);

    // ---- issue ALL X A-fragment loads first (latency hides under WtL stage)
    // A row = 32w + 16mt + c, k-cols 32kb+8g..+7
    const int arow = 32 * w + c;
    float4 xv[16];
#pragma unroll
    for (int mt = 0; mt < 2; ++mt)
#pragma unroll
        for (int kb = 0; kb < 4; ++kb) {
            const float* p = X + (size_t)(arow + 16 * mt) * DIN + kb * 32 + g * 8;
            xv[(mt * 4 + kb) * 2]     = *(const float4*)p;
            xv[(mt * 4 + kb) * 2 + 1] = *(const float4*)(p + 4);
        }

    // ---- stage WtL: wave w writes fragments idx=w, kb=0..3.
    // Fragment (idx,kb), lane (c,g) holds Wv[32kb+8g+j][16idx+c], j=0..7.
    // LDS byte = ((idx*4+kb)*64 + lane)*16 -> linear lane*16, conflict-free.
#pragma unroll
    for (int kb = 0; kb < 4; ++kb) {
        float f[8];
#pragma unroll
        for (int j = 0; j < 8; ++j)
            f[j] = wv[(kb * 32 + g * 8 + j) * DOUT + w * 16 + c];
        uint4v u;
#pragma unroll
        for (int e = 0; e < 4; ++e) u[e] = pk2(f[2 * e], f[2 * e + 1]);
        *(uint4v*)(WtL + ((size_t)((w * 4 + kb) * 64 + lane)) * 16) = u;
    }
    __syncthreads();   // WtL ready

    // ---- convert X fragments to packed bf16 (xv dies here)
    bf16x8 Af[2][4];
#pragma unroll
    for (int mt = 0; mt < 2; ++mt)
#pragma unroll
        for (int kb = 0; kb < 4; ++kb) {
            const int q = (mt * 4 + kb) * 2;
            uint4v u;
            u[0] = pk2(xv[q].x,     xv[q].y);
            u[1] = pk2(xv[q].z,     xv[q].w);
            u[2] = pk2(xv[q + 1].x, xv[q + 1].y);
            u[3] = pk2(xv[q + 1].z, xv[q + 1].w);
            Af[mt][kb] = __builtin_bit_cast(bf16x8, u);
        }

    // ---- stage 1: T rows [32w,32w+32) = X-panel * Wv  (B-frags from LDS)
    f32x4 Tacc[2][4] = {};
#pragma unroll
    for (int nt = 0; nt < 4; ++nt) {
        bf16x8 Bf[4];
#pragma unroll
        for (int kb = 0; kb < 4; ++kb)
            Bf[kb] = *(const bf16x8*)(WtL + ((size_t)((nt * 4 + kb) * 64 + lane)) * 16);
#pragma unroll
        for (int mt = 0; mt < 2; ++mt)
#pragma unroll
            for (int kb = 0; kb < 4; ++kb)
                Tacc[mt][nt] = MFMA(Af[mt][kb], Bf[kb], Tacc[mt][nt]);
    }

    // ---- pack + write T into Tt (v9 mapping, HW-verified):
    // T row k = 32w+16mt+4g+r, col 16nt+c ->
    // byte = ((w*4 + 2mt + (g>>1))*4 + nt)*256 + c*16 + (g&1)*8
#pragma unroll
    for (int mt = 0; mt < 2; ++mt)
#pragma unroll
        for (int nt = 0; nt < 4; ++nt) {
            uint2v p;
            p[0] = pk2(Tacc[mt][nt][0], Tacc[mt][nt][1]);
            p[1] = pk2(Tacc[mt][nt][2], Tacc[mt][nt][3]);
            const int byte = ((w * 4 + 2 * mt + (g >> 1)) * 4 + nt) * 256
                           + c * 16 + (g & 1) * 8;
            *(uint2v*)(Tt + byte) = p;
        }
    __syncthreads();

    // ---- stage 2: O = Wv^T * T ; wave w owns O cols 16w..16w+15.
    bf16x8 Bt[4];
#pragma unroll
    for (int kb = 0; kb < 4; ++kb)
        Bt[kb] = *(const bf16x8*)(Tt + ((kb * 4 + g) * 4 + w) * 256 + c * 16);

    float* ob = out + (size_t)blockIdx.x * (DOUT * DOUT)
              + (size_t)(g * 4) * DOUT + w * 16 + c;
#pragma unroll
    for (int mt2 = 0; mt2 < 4; ++mt2) {
        f32x4 acc = {0.f, 0.f, 0.f, 0.f};
#pragma unroll
        for (int kb = 0; kb < 4; ++kb) {
            bf16x8 Aw = *(const bf16x8*)(WtL + ((size_t)((mt2 * 4 + kb) * 64 + lane)) * 16);
            acc = MFMA(Aw, Bt[kb], acc);
        }
#pragma unroll
        for (int r = 0; r < 4; ++r)
            ob[(size_t)(mt2 * 16 + r) * DOUT] = acc[r];
    }
}

extern "C" void kernel_launch(void* const* d_in, const int* in_sizes, int n_in,
                              void* d_out, int out_size, void* d_ws, size_t ws_size,
                              hipStream_t stream)
{
    const float* x  = (const float*)d_in[0];   // (32,64,128,128) fp32
    const float* wv = (const float*)d_in[3];   // (128,64) fp32
    float* out = (float*)d_out;                // (2048,64,64) fp32

    (void)in_sizes; (void)n_in; (void)d_ws; (void)ws_size; (void)out_size;

    hipLaunchKernelGGL(spd_v10_kernel, dim3(GRID), dim3(BLOCK), 0, stream,
                       x, wv, out);
}